// Round 1
// baseline (432.061 us; speedup 1.0000x reference)
//
#include <hip/hip_runtime.h>

// KL(P || Q) for t-SNE, N=8192, D_LOW=2, dof=1.
// Single streaming pass over P; D recomputed from Y (cache-resident).
// KL = A + B*log(S) + C with
//   A = sum_{i!=j} P_ij * (log P_ij + log(1+d_ij))
//   B = sum_{i!=j} P_ij
//   S = sum_{i!=j} 1/(1+d_ij)
//   C = sum_i P_ii * (log P_ii - log EPS)     [diag of Q clamped to EPS]

static constexpr int NROWS = 8192;

__global__ __launch_bounds__(256) void kl_partial_kernel(
    const float* __restrict__ P, const float* __restrict__ Y,
    double* __restrict__ ws)
{
    const int nquads = (NROWS / 4) * NROWS;  // 16,777,216 float4s
    int tid = blockIdx.x * blockDim.x + threadIdx.x;
    int stride = gridDim.x * blockDim.x;

    const float4* __restrict__ P4 = reinterpret_cast<const float4*>(P);
    const float4* __restrict__ Y4 = reinterpret_cast<const float4*>(Y);
    const float2* __restrict__ Y2 = reinterpret_cast<const float2*>(Y);
    const float LOG_EPS = -27.63102111592855f;  // ln(1e-12)

    double sA = 0.0, sB = 0.0, sS = 0.0, sC = 0.0;

    for (int f = tid; f < nquads; f += stride) {
        int i  = f >> 11;         // 2048 quads per row
        int jq = f & 2047;
        int j0 = jq << 2;

        float4 p  = P4[f];
        float2 yi = Y2[i];
        float4 ya = Y4[jq << 1];        // y[j0], y[j0+1]
        float4 yb = Y4[(jq << 1) + 1];  // y[j0+2], y[j0+3]

        float pv[4]  = {p.x,  p.y,  p.z,  p.w};
        float yjx[4] = {ya.x, ya.z, yb.x, yb.z};
        float yjy[4] = {ya.y, ya.w, yb.y, yb.w};

#pragma unroll
        for (int k = 0; k < 4; ++k) {
            float dx  = yi.x - yjx[k];
            float dy  = yi.y - yjy[k];
            float opd = 1.0f + (dx * dx + dy * dy);  // 1 + ||y_i - y_j||^2
            if ((j0 + k) == i) {
                // diagonal: Q_ii clipped to EPS
                sC += (double)(pv[k] * (__logf(pv[k]) - LOG_EPS));
            } else {
                sS += (double)(1.0f / opd);
                sA += (double)(pv[k] * __logf(pv[k] * opd));
                sB += (double)pv[k];
            }
        }
    }

    // intra-wave butterfly reduce (64 lanes)
#pragma unroll
    for (int off = 32; off > 0; off >>= 1) {
        sA += __shfl_down(sA, off);
        sB += __shfl_down(sB, off);
        sS += __shfl_down(sS, off);
        sC += __shfl_down(sC, off);
    }

    __shared__ double red[4][4];  // [wave][accum]
    int wave = threadIdx.x >> 6;
    int lane = threadIdx.x & 63;
    if (lane == 0) {
        red[wave][0] = sA; red[wave][1] = sB;
        red[wave][2] = sS; red[wave][3] = sC;
    }
    __syncthreads();
    if (threadIdx.x == 0) {
        double a = 0.0, b = 0.0, s = 0.0, c = 0.0;
#pragma unroll
        for (int w = 0; w < 4; ++w) {
            a += red[w][0]; b += red[w][1]; s += red[w][2]; c += red[w][3];
        }
        atomicAdd(&ws[0], a);
        atomicAdd(&ws[1], b);
        atomicAdd(&ws[2], s);
        atomicAdd(&ws[3], c);
    }
}

__global__ void kl_final_kernel(const double* __restrict__ ws,
                                float* __restrict__ out)
{
    double A = ws[0], B = ws[1], S = ws[2], C = ws[3];
    out[0] = (float)(A + B * log(S) + C);
}

extern "C" void kernel_launch(void* const* d_in, const int* in_sizes, int n_in,
                              void* d_out, int out_size, void* d_ws, size_t ws_size,
                              hipStream_t stream) {
    const float* P = (const float*)d_in[0];
    const float* Y = (const float*)d_in[1];
    // d_in[2] is dof == 1 (fixed by setup_inputs); the 1/(1+d) form assumes it.
    double* ws = (double*)d_ws;

    // ws is re-poisoned to 0xAA before every launch — zero the 4 accumulators.
    hipMemsetAsync(d_ws, 0, 4 * sizeof(double), stream);

    dim3 grid(2048), block(256);
    hipLaunchKernelGGL(kl_partial_kernel, grid, block, 0, stream, P, Y, ws);
    hipLaunchKernelGGL(kl_final_kernel, dim3(1), dim3(1), 0, stream,
                       ws, (float*)d_out);
}